// Round 5
// baseline (917.175 us; speedup 1.0000x reference)
//
#include <hip/hip_runtime.h>
#include <math.h>

#define T_SEQ   1000
#define BATCH   8
#define DMODEL  512
#define NHEAD   8
#define DHEAD   64
#define FFDIM   2048
#define NLAYER  4
#define MROWS   (BATCH * T_SEQ)   // 8000
#define TCHUNK  25                // pooling pass-1 chunks (40 t each)

typedef __bf16 bf16x8 __attribute__((ext_vector_type(8)));
typedef __bf16 bf16x4 __attribute__((ext_vector_type(4)));
typedef float  f32x4  __attribute__((ext_vector_type(4)));
typedef float  f32x16 __attribute__((ext_vector_type(16)));

#define GL2LDS(g, l) \
    __builtin_amdgcn_global_load_lds((const __attribute__((address_space(1))) void*)(g), \
                                     (__attribute__((address_space(3))) void*)(l), 16, 0, 0)

// ---------------------------------------------------------------------------
// fp32 -> bf16 convert, 4 elems/thread.
// ---------------------------------------------------------------------------
__global__ __launch_bounds__(256)
void f2bf(const float* __restrict__ in, __bf16* __restrict__ out)
{
    int i = (blockIdx.x * 256 + threadIdx.x) * 4;
    float4 v = *(const float4*)(in + i);
    bf16x4 o;
    o[0] = (__bf16)v.x; o[1] = (__bf16)v.y; o[2] = (__bf16)v.z; o[3] = (__bf16)v.w;
    *(bf16x4*)(out + i) = o;
}

// ---------------------------------------------------------------------------
// bf16 MFMA GEMM: C(MxN) = A(MxK) @ B(NxK)^T + bias.
// 128x128 tile, BK=64, 4 waves (2x2), 64x64/wave, 16x16x32 MFMA.
// 2-phase double-buffered pipeline (T3 minimal): STAGE(t+1) issued BEFORE
// compute(t); ONE __syncthreads per K-step (its vmcnt(0) drain is covered
// by the compute phase).
// ---------------------------------------------------------------------------
template<bool WF32, bool WBF16, bool RELU>
__global__ __launch_bounds__(256)
void gemm_bf16(const __bf16* __restrict__ A, const __bf16* __restrict__ B,
               const float* __restrict__ bias, float* __restrict__ Cf,
               __bf16* __restrict__ Cb, int M, int N, int K)
{
    __shared__ __align__(16) __bf16 As[2][128 * 64];
    __shared__ __align__(16) __bf16 Bs[2][128 * 64];

    const int tid  = threadIdx.x;
    const int lane = tid & 63;
    const int w    = tid >> 6;
    const int wr   = w >> 1, wc = w & 1;
    const int row0 = blockIdx.y * 128;
    const int col0 = blockIdx.x * 128;

    size_t aoffg[4], boffg[4];
    int    ldso[4];
    #pragma unroll
    for (int p = 0; p < 4; ++p) {
        int bo = p * 4096 + tid * 16;
        int r  = bo >> 7;
        int cb = bo & 127;
        int ga = row0 + r; if (ga > M - 1) ga = M - 1;
        aoffg[p] = (size_t)ga * K * 2 + cb;
        boffg[p] = (size_t)(col0 + r) * K * 2 + cb;
        ldso[p]  = bo;
    }

    f32x4 acc[4][4];
    #pragma unroll
    for (int m = 0; m < 4; ++m)
        #pragma unroll
        for (int n = 0; n < 4; ++n) acc[m][n] = (f32x4)0.f;

    const char* gA = (const char*)A;
    const char* gB = (const char*)B;

    const int nt = K >> 6;   // K/64 steps

    // prologue: stage tile 0 into buffer 0
    {
        char* lA = (char*)As[0];
        char* lB = (char*)Bs[0];
        #pragma unroll
        for (int p = 0; p < 4; ++p) {
            GL2LDS(gA + aoffg[p], lA + ldso[p]);
            GL2LDS(gB + boffg[p], lB + ldso[p]);
        }
    }
    __syncthreads();

    int cur = 0;
    for (int t = 0; t < nt; ++t) {
        // issue next-tile loads into the other buffer (latency hides under MFMA)
        if (t + 1 < nt) {
            const size_t kb = (size_t)(t + 1) << 7;   // (t+1)*64 elems * 2B
            char* lA = (char*)As[cur ^ 1];
            char* lB = (char*)Bs[cur ^ 1];
            #pragma unroll
            for (int p = 0; p < 4; ++p) {
                GL2LDS(gA + aoffg[p] + kb, lA + ldso[p]);
                GL2LDS(gB + boffg[p] + kb, lB + ldso[p]);
            }
        }
        // compute current tile
        const __bf16* as = As[cur];
        const __bf16* bs = Bs[cur];
        #pragma unroll
        for (int ks = 0; ks < 2; ++ks) {
            bf16x8 af[4], bfr[4];
            #pragma unroll
            for (int m = 0; m < 4; ++m) {
                int rr = wr * 64 + m * 16 + (lane & 15);
                af[m] = *(const bf16x8*)(as + rr * 64 + ks * 32 + (lane >> 4) * 8);
            }
            #pragma unroll
            for (int n = 0; n < 4; ++n) {
                int rr = wc * 64 + n * 16 + (lane & 15);
                bfr[n] = *(const bf16x8*)(bs + rr * 64 + ks * 32 + (lane >> 4) * 8);
            }
            #pragma unroll
            for (int m = 0; m < 4; ++m)
                #pragma unroll
                for (int n = 0; n < 4; ++n)
                    acc[m][n] = __builtin_amdgcn_mfma_f32_16x16x32_bf16(af[m], bfr[n], acc[m][n], 0, 0, 0);
        }
        __syncthreads();   // drains vmcnt(0): next tile resident; all waves done reading cur
        cur ^= 1;
    }

    const int crow = (lane >> 4) * 4;
    const int ccol = lane & 15;
    #pragma unroll
    for (int n = 0; n < 4; ++n) {
        const int gc = col0 + wc * 64 + n * 16 + ccol;
        const float bv = bias[gc];
        #pragma unroll
        for (int m = 0; m < 4; ++m) {
            const int gr0 = row0 + wr * 64 + m * 16 + crow;
            #pragma unroll
            for (int r = 0; r < 4; ++r) {
                const int gr = gr0 + r;
                if (gr >= M) continue;
                float v = acc[m][n][r] + bv;
                if (RELU) v = fmaxf(v, 0.f);
                if (WF32)  Cf[(size_t)gr * N + gc] = v;
                if (WBF16) Cb[(size_t)gr * N + gc] = (__bf16)v;
            }
        }
    }
}

// ---------------------------------------------------------------------------
// Add sinusoidal PE in place (fp32) + write bf16 shadow.
// ---------------------------------------------------------------------------
__global__ __launch_bounds__(256)
void add_pe(float* __restrict__ hbuf, __bf16* __restrict__ hb)
{
    int idx = blockIdx.x * 256 + threadIdx.x;
    int d   = idx & (DMODEL - 1);
    int t   = (idx >> 9) % T_SEQ;
    float freq = expf((float)(d & ~1) * (-9.210340371976184f / (float)DMODEL));
    float ang  = (float)t * freq;
    float pe   = (d & 1) ? cosf(ang) : sinf(ang);
    float v = hbuf[idx] + pe;
    hbuf[idx] = v;
    hb[idx]   = (__bf16)v;
}

// ---------------------------------------------------------------------------
// MFMA flash attention over the band, 32x32x16, swapped-operand structure.
// ---------------------------------------------------------------------------
__global__ __launch_bounds__(256)
void attn_mfma(const __bf16* __restrict__ qkv, __bf16* __restrict__ o)
{
    const int wv   = (blockIdx.x << 2) + (threadIdx.x >> 6);
    const int lane = threadIdx.x & 63;
    const int qt   = wv & 31;
    const int hh   = (wv >> 5) & 7;
    const int b    = wv >> 8;
    const int qb   = qt * 32;
    const int half = lane >> 5;
    const int ql   = lane & 31;
    const int i    = qb + ql;
    const int iq   = (i < T_SEQ) ? i : (T_SEQ - 1);

    const int RS = 3 * DMODEL;
    const __bf16* Q = qkv + (size_t)b * T_SEQ * RS + hh * DHEAD;
    const __bf16* K = Q + DMODEL;
    const __bf16* V = Q + 2 * DMODEL;

    bf16x8 qf[4];
    {
        const __bf16* qrow = Q + (size_t)iq * RS + half * 8;
        #pragma unroll
        for (int ds = 0; ds < 4; ++ds)
            qf[ds] = *(const bf16x8*)(qrow + ds * 16);
    }

    const int w = 25 * (hh + 1);
    const int kb_lo = (qb - w > 0 ? qb - w : 0) & ~31;
    const int kb_hi = (qb + 31 + w < T_SEQ - 1) ? (qb + 31 + w) : (T_SEQ - 1);
    const int  spanv = (2 * w < T_SEQ - 1 - i + w) ? 2 * w : (T_SEQ - 1 - i + w);
    const unsigned span = (unsigned)spanv;
    const float C2 = 0.125f * 1.44269504089f;

    float m2 = -1e9f, l = 0.f;
    f32x16 oa0 = (f32x16)0.f, oa1 = (f32x16)0.f;

    for (int kb = kb_lo; kb <= kb_hi; kb += 32) {
        f32x16 sv = (f32x16)0.f;
        {
            int krow = kb + ql; if (krow > T_SEQ - 1) krow = T_SEQ - 1;
            const __bf16* kr = K + (size_t)krow * RS + half * 8;
            #pragma unroll
            for (int ds = 0; ds < 4; ++ds) {
                bf16x8 kf = *(const bf16x8*)(kr + ds * 16);
                sv = __builtin_amdgcn_mfma_f32_32x32x16_bf16(kf, qf[ds], sv, 0, 0, 0);
            }
        }

        const int base = kb - i + w;
        float s2[16];
        #pragma unroll
        for (int r = 0; r < 16; ++r) {
            const int kr = (r & 3) + 8 * (r >> 2) + 4 * half;
            const unsigned jrel = (unsigned)(base + kr);
            s2[r] = (jrel <= span) ? sv[r] * C2 : -1e9f;
        }

        float mx = s2[0];
        #pragma unroll
        for (int r = 1; r < 16; ++r) mx = fmaxf(mx, s2[r]);
        mx = fmaxf(mx, __shfl_xor(mx, 32, 64));

        if (!__all(mx <= m2 + 8.0f)) {
            const float mnew  = fmaxf(m2, mx);
            const float scale = exp2f(m2 - mnew);
            m2 = mnew;
            l *= scale;
            #pragma unroll
            for (int r = 0; r < 16; ++r) {
                const int qsrc = (r & 3) + 8 * (r >> 2) + 4 * half;
                const float sc = __shfl(scale, qsrc, 64);
                oa0[r] *= sc;
                oa1[r] *= sc;
            }
        }

        float p[16];
        float ps = 0.f;
        #pragma unroll
        for (int r = 0; r < 16; ++r) { p[r] = exp2f(s2[r] - m2); ps += p[r]; }
        ps += __shfl_xor(ps, 32, 64);
        l += ps;

        unsigned pk[8];
        #pragma unroll
        for (int t = 0; t < 8; ++t) {
            union { unsigned u; __bf16 h[2]; } cv;
            cv.h[0] = (__bf16)p[2 * t];
            cv.h[1] = (__bf16)p[2 * t + 1];
            pk[t] = cv.u;
        }
        unsigned y[8];
        #pragma unroll
        for (int t = 0; t < 8; ++t)
            y[t] = (unsigned)__shfl_xor((int)pk[t], 32, 64);

        union { unsigned u[4]; bf16x8 v; } pa0, pa1;
        if (half == 0) {
            pa0.u[0] = pk[0]; pa0.u[1] = pk[1]; pa0.u[2] = y[0];  pa0.u[3] = y[1];
            pa1.u[0] = pk[4]; pa1.u[1] = pk[5]; pa1.u[2] = y[4];  pa1.u[3] = y[5];
        } else {
            pa0.u[0] = y[2];  pa0.u[1] = y[3];  pa0.u[2] = pk[2]; pa0.u[3] = pk[3];
            pa1.u[0] = y[6];  pa1.u[1] = y[7];  pa1.u[2] = pk[6]; pa1.u[3] = pk[7];
        }

        #pragma unroll
        for (int ks = 0; ks < 2; ++ks) {
            const int R0 = kb + ks * 16 + half * 8;
            #pragma unroll
            for (int dh = 0; dh < 2; ++dh) {
                bf16x8 vf;
                const __bf16* vcol = V + dh * 32 + ql;
                #pragma unroll
                for (int j = 0; j < 8; ++j) {
                    int rr = R0 + j; if (rr > T_SEQ - 1) rr = T_SEQ - 1;
                    vf[j] = vcol[(size_t)rr * RS];
                }
                if (dh == 0)
                    oa0 = __builtin_amdgcn_mfma_f32_32x32x16_bf16(ks ? pa1.v : pa0.v, vf, oa0, 0, 0, 0);
                else
                    oa1 = __builtin_amdgcn_mfma_f32_32x32x16_bf16(ks ? pa1.v : pa0.v, vf, oa1, 0, 0, 0);
            }
        }
    }

    const float rinv = 1.f / l;
    __bf16* ob = o + ((size_t)b * T_SEQ) * DMODEL + hh * DHEAD;
    #pragma unroll
    for (int r = 0; r < 16; ++r) {
        const int q   = (r & 3) + 8 * (r >> 2) + 4 * half;
        const int row = qb + q;
        const float ri = __shfl(rinv, q, 64);
        if (row < T_SEQ) {
            ob[(size_t)row * DMODEL + ql]      = (__bf16)(oa0[r] * ri);
            ob[(size_t)row * DMODEL + 32 + ql] = (__bf16)(oa1[r] * ri);
        }
    }
}

// ---------------------------------------------------------------------------
// h = LayerNorm(h + t) * g + b (fp32 residual stream) + bf16 shadow.
// ---------------------------------------------------------------------------
__global__ __launch_bounds__(256)
void add_ln(float* __restrict__ hbuf, const float* __restrict__ tbuf,
            const float* __restrict__ g, const float* __restrict__ b,
            __bf16* __restrict__ hb)
{
    const int row  = blockIdx.x * 4 + (threadIdx.x >> 6);
    const int lane = threadIdx.x & 63;
    float*       hp = hbuf + (size_t)row * DMODEL + lane * 8;
    const float* tp = tbuf + (size_t)row * DMODEL + lane * 8;

    float xv[8];
    float4 h0 = *(const float4*)hp;   float4 h1 = *(const float4*)(hp + 4);
    float4 t0 = *(const float4*)tp;   float4 t1 = *(const float4*)(tp + 4);
    xv[0] = h0.x + t0.x; xv[1] = h0.y + t0.y; xv[2] = h0.z + t0.z; xv[3] = h0.w + t0.w;
    xv[4] = h1.x + t1.x; xv[5] = h1.y + t1.y; xv[6] = h1.z + t1.z; xv[7] = h1.w + t1.w;

    float s = 0.f;
    #pragma unroll
    for (int j = 0; j < 8; ++j) s += xv[j];
    #pragma unroll
    for (int off = 32; off >= 1; off >>= 1) s += __shfl_xor(s, off, 64);
    float mean = s * (1.f / DMODEL);

    float vs = 0.f;
    #pragma unroll
    for (int j = 0; j < 8; ++j) { float d = xv[j] - mean; vs += d * d; }
    #pragma unroll
    for (int off = 32; off >= 1; off >>= 1) vs += __shfl_xor(vs, off, 64);
    float rstd = rsqrtf(vs * (1.f / DMODEL) + 1e-5f);

    float4 g0 = *(const float4*)(g + lane * 8);
    float4 g1 = *(const float4*)(g + lane * 8 + 4);
    float4 b0 = *(const float4*)(b + lane * 8);
    float4 b1 = *(const float4*)(b + lane * 8 + 4);
    float gg[8] = {g0.x, g0.y, g0.z, g0.w, g1.x, g1.y, g1.z, g1.w};
    float bb[8] = {b0.x, b0.y, b0.z, b0.w, b1.x, b1.y, b1.z, b1.w};

    float outv[8];
    bf16x8 ob;
    #pragma unroll
    for (int j = 0; j < 8; ++j) {
        outv[j] = (xv[j] - mean) * rstd * gg[j] + bb[j];
        ob[j] = (__bf16)outv[j];
    }
    *(float4*)hp       = *(float4*)&outv[0];
    *(float4*)(hp + 4) = *(float4*)&outv[4];
    *(bf16x8*)(hb + (size_t)row * DMODEL + lane * 8) = ob;
}

// ---------------------------------------------------------------------------
// Max-pool pass 1: grid (BATCH, TCHUNK).
// ---------------------------------------------------------------------------
__global__ __launch_bounds__(256)
void pool_p1(const float* __restrict__ hbuf, float* __restrict__ part)
{
    const int bb  = blockIdx.x;
    const int tc  = blockIdx.y;
    const int tid = threadIdx.x;
    const int t0  = tc * (T_SEQ / TCHUNK);
    const float* p = hbuf + ((size_t)bb * T_SEQ + t0) * DMODEL;

    float mx0 = -3.4e38f, mx1 = -3.4e38f;
    for (int t = 0; t < T_SEQ / TCHUNK; ++t) {
        mx0 = fmaxf(mx0, p[(size_t)t * DMODEL + tid]);
        mx1 = fmaxf(mx1, p[(size_t)t * DMODEL + 256 + tid]);
    }
    float* q = part + ((size_t)bb * TCHUNK + tc) * DMODEL;
    q[tid]       = mx0;
    q[tid + 256] = mx1;
}

// ---------------------------------------------------------------------------
// Max-pool pass 2 + classifier + log_softmax. One block per batch item.
// ---------------------------------------------------------------------------
__global__ __launch_bounds__(256)
void pool_p2(const float* __restrict__ part, const float* __restrict__ Wcls,
             const float* __restrict__ bcls, float* __restrict__ out)
{
    __shared__ float pooled[DMODEL];
    __shared__ float logits[8];
    const int bb  = blockIdx.x;
    const int tid = threadIdx.x;

    const float* q = part + (size_t)bb * TCHUNK * DMODEL;
    #pragma unroll
    for (int u = 0; u < 2; ++u) {
        const int d = tid + u * 256;
        float mx = -3.4e38f;
        for (int c = 0; c < TCHUNK; ++c) mx = fmaxf(mx, q[(size_t)c * DMODEL + d]);
        pooled[d] = mx;
    }
    __syncthreads();

    const int cls  = tid >> 5;
    const int lsub = tid & 31;
    const float* wr = Wcls + cls * DMODEL;
    float s = 0.f;
    #pragma unroll
    for (int u = 0; u < 16; ++u) {
        const int d = lsub + u * 32;
        s = fmaf(pooled[d], wr[d], s);
    }
    #pragma unroll
    for (int off = 16; off >= 1; off >>= 1) s += __shfl_xor(s, off, 32);
    if (lsub == 0) logits[cls] = s + bcls[cls];
    __syncthreads();

    if (tid == 0) {
        float mx = logits[0];
        for (int c = 1; c < 8; ++c) mx = fmaxf(mx, logits[c]);
        float se = 0.f;
        for (int c = 0; c < 8; ++c) se += expf(logits[c] - mx);
        float lse = logf(se) + mx;
        for (int c = 0; c < 8; ++c) out[bb * 8 + c] = logits[c] - lse;
    }
}

// ---------------------------------------------------------------------------
extern "C" void kernel_launch(void* const* d_in, const int* in_sizes, int n_in,
                              void* d_out, int out_size, void* d_ws, size_t ws_size,
                              hipStream_t stream)
{
    const float* x    = (const float*)d_in[0];
    const float* Wemb = (const float*)d_in[1];
    const float* bemb = (const float*)d_in[2];
    const float* Wqkv = (const float*)d_in[3];
    const float* bqkv = (const float*)d_in[4];
    const float* Wo   = (const float*)d_in[5];
    const float* bo   = (const float*)d_in[6];
    const float* W1   = (const float*)d_in[7];
    const float* b1f  = (const float*)d_in[8];
    const float* W2   = (const float*)d_in[9];
    const float* b2f  = (const float*)d_in[10];
    const float* g1   = (const float*)d_in[11];
    const float* be1  = (const float*)d_in[12];
    const float* g2   = (const float*)d_in[13];
    const float* be2  = (const float*)d_in[14];
    const float* Wcls = (const float*)d_in[15];
    const float* bcls = (const float*)d_in[16];
    float* out = (float*)d_out;

    // -------- workspace layout --------
    float*  h    = (float*)d_ws;                       // 8000x512 f32
    float*  tmpF = h + (size_t)MROWS * DMODEL;         // 8000x512 f32 (also pool partials)
    __bf16* hb   = (__bf16*)(tmpF + (size_t)MROWS * DMODEL);   // 8000x512
    __bf16* qkvb = hb + (size_t)MROWS * DMODEL;        // 8000x1536
    __bf16* attb = qkvb + (size_t)MROWS * 3 * DMODEL;  // 8000x512
    __bf16* ff1b = qkvb;                               // alias: 8000x2048
    __bf16* xb   = attb + (size_t)MROWS * DMODEL;      // 8000x256
    __bf16* wb   = xb + (size_t)MROWS * 256;
    __bf16* wEmb = wb;
    __bf16* wQKV = wEmb + 512 * 256;
    __bf16* wWo  = wQKV + (size_t)NLAYER * 3 * DMODEL * DMODEL;
    __bf16* wW1  = wWo  + (size_t)NLAYER * DMODEL * DMODEL;
    __bf16* wW2  = wW1  + (size_t)NLAYER * FFDIM * DMODEL;

    dim3 blk(256);

    f2bf<<<dim3(MROWS * 256 / 1024), blk, 0, stream>>>(x, xb);
    f2bf<<<dim3(512 * 256 / 1024), blk, 0, stream>>>(Wemb, wEmb);
    f2bf<<<dim3(NLAYER * 3 * DMODEL * DMODEL / 1024), blk, 0, stream>>>(Wqkv, wQKV);
    f2bf<<<dim3(NLAYER * DMODEL * DMODEL / 1024), blk, 0, stream>>>(Wo, wWo);
    f2bf<<<dim3(NLAYER * FFDIM * DMODEL / 1024), blk, 0, stream>>>(W1, wW1);
    f2bf<<<dim3(NLAYER * DMODEL * FFDIM / 1024), blk, 0, stream>>>(W2, wW2);

    gemm_bf16<true, false, false><<<dim3(4, 63), blk, 0, stream>>>(
        xb, wEmb, bemb, h, nullptr, MROWS, DMODEL, 256);
    add_pe<<<dim3(MROWS * DMODEL / 256), blk, 0, stream>>>(h, hb);

    for (int l = 0; l < NLAYER; ++l) {
        gemm_bf16<false, true, false><<<dim3(12, 63), blk, 0, stream>>>(
            hb, wQKV + (size_t)l * 3 * DMODEL * DMODEL, bqkv + (size_t)l * 3 * DMODEL,
            nullptr, qkvb, MROWS, 3 * DMODEL, DMODEL);
        attn_mfma<<<dim3(512), blk, 0, stream>>>(qkvb, attb);
        gemm_bf16<true, false, false><<<dim3(4, 63), blk, 0, stream>>>(
            attb, wWo + (size_t)l * DMODEL * DMODEL, bo + (size_t)l * DMODEL,
            tmpF, nullptr, MROWS, DMODEL, DMODEL);
        add_ln<<<dim3(MROWS / 4), blk, 0, stream>>>(
            h, tmpF, g1 + (size_t)l * DMODEL, be1 + (size_t)l * DMODEL, hb);
        gemm_bf16<false, true, true><<<dim3(16, 63), blk, 0, stream>>>(
            hb, wW1 + (size_t)l * FFDIM * DMODEL, b1f + (size_t)l * FFDIM,
            nullptr, ff1b, MROWS, FFDIM, DMODEL);
        gemm_bf16<true, false, false><<<dim3(4, 63), blk, 0, stream>>>(
            ff1b, wW2 + (size_t)l * DMODEL * FFDIM, b2f + (size_t)l * DMODEL,
            tmpF, nullptr, MROWS, DMODEL, FFDIM);
        add_ln<<<dim3(MROWS / 4), blk, 0, stream>>>(
            h, tmpF, g2 + (size_t)l * DMODEL, be2 + (size_t)l * DMODEL, hb);
    }

    pool_p1<<<dim3(BATCH, TCHUNK), blk, 0, stream>>>(h, tmpF);
    pool_p2<<<dim3(BATCH), blk, 0, stream>>>(tmpF, Wcls, bcls, out);
}

// Round 6
// 870.691 us; speedup vs baseline: 1.0534x; 1.0534x over previous
//
#include <hip/hip_runtime.h>
#include <math.h>

#define T_SEQ   1000
#define BATCH   8
#define DMODEL  512
#define NHEAD   8
#define DHEAD   64
#define FFDIM   2048
#define NLAYER  4
#define MROWS   (BATCH * T_SEQ)   // 8000
#define TCHUNK  25                // pooling pass-1 chunks (40 t each)

typedef __bf16 bf16x8 __attribute__((ext_vector_type(8)));
typedef __bf16 bf16x4 __attribute__((ext_vector_type(4)));
typedef float  f32x4  __attribute__((ext_vector_type(4)));
typedef float  f32x16 __attribute__((ext_vector_type(16)));

#define GL2LDS(g, l) \
    __builtin_amdgcn_global_load_lds((const __attribute__((address_space(1))) void*)(g), \
                                     (__attribute__((address_space(3))) void*)(l), 16, 0, 0)

// ---------------------------------------------------------------------------
// fp32 -> bf16 convert, 4 elems/thread.
// ---------------------------------------------------------------------------
__global__ __launch_bounds__(256)
void f2bf(const float* __restrict__ in, __bf16* __restrict__ out)
{
    int i = (blockIdx.x * 256 + threadIdx.x) * 4;
    float4 v = *(const float4*)(in + i);
    bf16x4 o;
    o[0] = (__bf16)v.x; o[1] = (__bf16)v.y; o[2] = (__bf16)v.z; o[3] = (__bf16)v.w;
    *(bf16x4*)(out + i) = o;
}

// ---------------------------------------------------------------------------
// bf16 MFMA GEMM: C(MxN) = A(MxK) @ B(NxK)^T + bias.
// TM x 128 tile (TM = 64 or 128), BK=64, 4 waves (2x2), 2-phase dbuf.
// TM=64 for N-small GEMMs: doubles block count -> >=2 blocks/CU so
// cross-block wave overlap (m114) hides the per-K-step barrier drain.
// ---------------------------------------------------------------------------
template<int TM, bool WF32, bool WBF16, bool RELU>
__global__ __launch_bounds__(256)
void gemm_bf16(const __bf16* __restrict__ A, const __bf16* __restrict__ B,
               const float* __restrict__ bias, float* __restrict__ Cf,
               __bf16* __restrict__ Cb, int M, int N, int K)
{
    constexpr int MR = TM / 32;        // m-fragments per wave (wave rows = TM/2)
    constexpr int PA = TM / 32;        // A staging passes (TM*128B / 4096B)
    __shared__ __align__(16) __bf16 As[2][TM * 64];
    __shared__ __align__(16) __bf16 Bs[2][128 * 64];

    const int tid  = threadIdx.x;
    const int lane = tid & 63;
    const int w    = tid >> 6;
    const int wr   = w >> 1, wc = w & 1;
    const int row0 = blockIdx.y * TM;
    const int col0 = blockIdx.x * 128;

    size_t aoffg[4], boffg[4];
    int    ldso[4];
    #pragma unroll
    for (int p = 0; p < 4; ++p) {
        int bo = p * 4096 + tid * 16;
        int r  = bo >> 7;            // row (128B per row of 64 bf16)
        int cb = bo & 127;
        if (p < PA) {
            int ga = row0 + r; if (ga > M - 1) ga = M - 1;
            aoffg[p] = (size_t)ga * K * 2 + cb;
        }
        boffg[p] = (size_t)(col0 + r) * K * 2 + cb;
        ldso[p]  = bo;
    }

    f32x4 acc[MR][4];
    #pragma unroll
    for (int m = 0; m < MR; ++m)
        #pragma unroll
        for (int n = 0; n < 4; ++n) acc[m][n] = (f32x4)0.f;

    const char* gA = (const char*)A;
    const char* gB = (const char*)B;

    const int nt = K >> 6;

    // prologue: stage tile 0 into buffer 0
    {
        char* lA = (char*)As[0];
        char* lB = (char*)Bs[0];
        #pragma unroll
        for (int p = 0; p < PA; ++p) GL2LDS(gA + aoffg[p], lA + ldso[p]);
        #pragma unroll
        for (int p = 0; p < 4;  ++p) GL2LDS(gB + boffg[p], lB + ldso[p]);
    }
    __syncthreads();

    int cur = 0;
    for (int t = 0; t < nt; ++t) {
        if (t + 1 < nt) {
            const size_t kb = (size_t)(t + 1) << 7;
            char* lA = (char*)As[cur ^ 1];
            char* lB = (char*)Bs[cur ^ 1];
            #pragma unroll
            for (int p = 0; p < PA; ++p) GL2LDS(gA + aoffg[p] + kb, lA + ldso[p]);
            #pragma unroll
            for (int p = 0; p < 4;  ++p) GL2LDS(gB + boffg[p] + kb, lB + ldso[p]);
        }
        const __bf16* as = As[cur];
        const __bf16* bs = Bs[cur];
        #pragma unroll
        for (int ks = 0; ks < 2; ++ks) {
            bf16x8 af[MR], bfr[4];
            #pragma unroll
            for (int m = 0; m < MR; ++m) {
                int rr = wr * (TM / 2) + m * 16 + (lane & 15);
                af[m] = *(const bf16x8*)(as + rr * 64 + ks * 32 + (lane >> 4) * 8);
            }
            #pragma unroll
            for (int n = 0; n < 4; ++n) {
                int rr = wc * 64 + n * 16 + (lane & 15);
                bfr[n] = *(const bf16x8*)(bs + rr * 64 + ks * 32 + (lane >> 4) * 8);
            }
            #pragma unroll
            for (int m = 0; m < MR; ++m)
                #pragma unroll
                for (int n = 0; n < 4; ++n)
                    acc[m][n] = __builtin_amdgcn_mfma_f32_16x16x32_bf16(af[m], bfr[n], acc[m][n], 0, 0, 0);
        }
        __syncthreads();
        cur ^= 1;
    }

    const int crow = (lane >> 4) * 4;
    const int ccol = lane & 15;
    #pragma unroll
    for (int n = 0; n < 4; ++n) {
        const int gc = col0 + wc * 64 + n * 16 + ccol;
        const float bv = bias[gc];
        #pragma unroll
        for (int m = 0; m < MR; ++m) {
            const int gr0 = row0 + wr * (TM / 2) + m * 16 + crow;
            #pragma unroll
            for (int r = 0; r < 4; ++r) {
                const int gr = gr0 + r;
                if (gr >= M) continue;
                float v = acc[m][n][r] + bv;
                if (RELU) v = fmaxf(v, 0.f);
                if (WF32)  Cf[(size_t)gr * N + gc] = v;
                if (WBF16) Cb[(size_t)gr * N + gc] = (__bf16)v;
            }
        }
    }
}

// ---------------------------------------------------------------------------
// Add sinusoidal PE in place (fp32) + write bf16 shadow.
// ---------------------------------------------------------------------------
__global__ __launch_bounds__(256)
void add_pe(float* __restrict__ hbuf, __bf16* __restrict__ hb)
{
    int idx = blockIdx.x * 256 + threadIdx.x;
    int d   = idx & (DMODEL - 1);
    int t   = (idx >> 9) % T_SEQ;
    float freq = expf((float)(d & ~1) * (-9.210340371976184f / (float)DMODEL));
    float ang  = (float)t * freq;
    float pe   = (d & 1) ? cosf(ang) : sinf(ang);
    float v = hbuf[idx] + pe;
    hbuf[idx] = v;
    hb[idx]   = (__bf16)v;
}

// ---------------------------------------------------------------------------
// MFMA flash attention over the band, 32x32x16, swapped-operand structure.
// ---------------------------------------------------------------------------
__global__ __launch_bounds__(256)
void attn_mfma(const __bf16* __restrict__ qkv, __bf16* __restrict__ o)
{
    const int wv   = (blockIdx.x << 2) + (threadIdx.x >> 6);
    const int lane = threadIdx.x & 63;
    const int qt   = wv & 31;
    const int hh   = (wv >> 5) & 7;
    const int b    = wv >> 8;
    const int qb   = qt * 32;
    const int half = lane >> 5;
    const int ql   = lane & 31;
    const int i    = qb + ql;
    const int iq   = (i < T_SEQ) ? i : (T_SEQ - 1);

    const int RS = 3 * DMODEL;
    const __bf16* Q = qkv + (size_t)b * T_SEQ * RS + hh * DHEAD;
    const __bf16* K = Q + DMODEL;
    const __bf16* V = Q + 2 * DMODEL;

    bf16x8 qf[4];
    {
        const __bf16* qrow = Q + (size_t)iq * RS + half * 8;
        #pragma unroll
        for (int ds = 0; ds < 4; ++ds)
            qf[ds] = *(const bf16x8*)(qrow + ds * 16);
    }

    const int w = 25 * (hh + 1);
    const int kb_lo = (qb - w > 0 ? qb - w : 0) & ~31;
    const int kb_hi = (qb + 31 + w < T_SEQ - 1) ? (qb + 31 + w) : (T_SEQ - 1);
    const int  spanv = (2 * w < T_SEQ - 1 - i + w) ? 2 * w : (T_SEQ - 1 - i + w);
    const unsigned span = (unsigned)spanv;
    const float C2 = 0.125f * 1.44269504089f;

    float m2 = -1e9f, l = 0.f;
    f32x16 oa0 = (f32x16)0.f, oa1 = (f32x16)0.f;

    for (int kb = kb_lo; kb <= kb_hi; kb += 32) {
        f32x16 sv = (f32x16)0.f;
        {
            int krow = kb + ql; if (krow > T_SEQ - 1) krow = T_SEQ - 1;
            const __bf16* kr = K + (size_t)krow * RS + half * 8;
            #pragma unroll
            for (int ds = 0; ds < 4; ++ds) {
                bf16x8 kf = *(const bf16x8*)(kr + ds * 16);
                sv = __builtin_amdgcn_mfma_f32_32x32x16_bf16(kf, qf[ds], sv, 0, 0, 0);
            }
        }

        const int base = kb - i + w;
        float s2[16];
        #pragma unroll
        for (int r = 0; r < 16; ++r) {
            const int kr = (r & 3) + 8 * (r >> 2) + 4 * half;
            const unsigned jrel = (unsigned)(base + kr);
            s2[r] = (jrel <= span) ? sv[r] * C2 : -1e9f;
        }

        float mx = s2[0];
        #pragma unroll
        for (int r = 1; r < 16; ++r) mx = fmaxf(mx, s2[r]);
        mx = fmaxf(mx, __shfl_xor(mx, 32, 64));

        if (!__all(mx <= m2 + 8.0f)) {
            const float mnew  = fmaxf(m2, mx);
            const float scale = exp2f(m2 - mnew);
            m2 = mnew;
            l *= scale;
            #pragma unroll
            for (int r = 0; r < 16; ++r) {
                const int qsrc = (r & 3) + 8 * (r >> 2) + 4 * half;
                const float sc = __shfl(scale, qsrc, 64);
                oa0[r] *= sc;
                oa1[r] *= sc;
            }
        }

        float p[16];
        float ps = 0.f;
        #pragma unroll
        for (int r = 0; r < 16; ++r) { p[r] = exp2f(s2[r] - m2); ps += p[r]; }
        ps += __shfl_xor(ps, 32, 64);
        l += ps;

        unsigned pk[8];
        #pragma unroll
        for (int t = 0; t < 8; ++t) {
            union { unsigned u; __bf16 h[2]; } cv;
            cv.h[0] = (__bf16)p[2 * t];
            cv.h[1] = (__bf16)p[2 * t + 1];
            pk[t] = cv.u;
        }
        unsigned y[8];
        #pragma unroll
        for (int t = 0; t < 8; ++t)
            y[t] = (unsigned)__shfl_xor((int)pk[t], 32, 64);

        union { unsigned u[4]; bf16x8 v; } pa0, pa1;
        if (half == 0) {
            pa0.u[0] = pk[0]; pa0.u[1] = pk[1]; pa0.u[2] = y[0];  pa0.u[3] = y[1];
            pa1.u[0] = pk[4]; pa1.u[1] = pk[5]; pa1.u[2] = y[4];  pa1.u[3] = y[5];
        } else {
            pa0.u[0] = y[2];  pa0.u[1] = y[3];  pa0.u[2] = pk[2]; pa0.u[3] = pk[3];
            pa1.u[0] = y[6];  pa1.u[1] = y[7];  pa1.u[2] = pk[6]; pa1.u[3] = pk[7];
        }

        #pragma unroll
        for (int ks = 0; ks < 2; ++ks) {
            const int R0 = kb + ks * 16 + half * 8;
            #pragma unroll
            for (int dh = 0; dh < 2; ++dh) {
                bf16x8 vf;
                const __bf16* vcol = V + dh * 32 + ql;
                #pragma unroll
                for (int j = 0; j < 8; ++j) {
                    int rr = R0 + j; if (rr > T_SEQ - 1) rr = T_SEQ - 1;
                    vf[j] = vcol[(size_t)rr * RS];
                }
                if (dh == 0)
                    oa0 = __builtin_amdgcn_mfma_f32_32x32x16_bf16(ks ? pa1.v : pa0.v, vf, oa0, 0, 0, 0);
                else
                    oa1 = __builtin_amdgcn_mfma_f32_32x32x16_bf16(ks ? pa1.v : pa0.v, vf, oa1, 0, 0, 0);
            }
        }
    }

    const float rinv = 1.f / l;
    __bf16* ob = o + ((size_t)b * T_SEQ) * DMODEL + hh * DHEAD;
    #pragma unroll
    for (int r = 0; r < 16; ++r) {
        const int q   = (r & 3) + 8 * (r >> 2) + 4 * half;
        const int row = qb + q;
        const float ri = __shfl(rinv, q, 64);
        if (row < T_SEQ) {
            ob[(size_t)row * DMODEL + ql]      = (__bf16)(oa0[r] * ri);
            ob[(size_t)row * DMODEL + 32 + ql] = (__bf16)(oa1[r] * ri);
        }
    }
}

// ---------------------------------------------------------------------------
// h = LayerNorm(h + t) * g + b (fp32 residual stream) + bf16 shadow.
// ---------------------------------------------------------------------------
__global__ __launch_bounds__(256)
void add_ln(float* __restrict__ hbuf, const float* __restrict__ tbuf,
            const float* __restrict__ g, const float* __restrict__ b,
            __bf16* __restrict__ hb)
{
    const int row  = blockIdx.x * 4 + (threadIdx.x >> 6);
    const int lane = threadIdx.x & 63;
    float*       hp = hbuf + (size_t)row * DMODEL + lane * 8;
    const float* tp = tbuf + (size_t)row * DMODEL + lane * 8;

    float xv[8];
    float4 h0 = *(const float4*)hp;   float4 h1 = *(const float4*)(hp + 4);
    float4 t0 = *(const float4*)tp;   float4 t1 = *(const float4*)(tp + 4);
    xv[0] = h0.x + t0.x; xv[1] = h0.y + t0.y; xv[2] = h0.z + t0.z; xv[3] = h0.w + t0.w;
    xv[4] = h1.x + t1.x; xv[5] = h1.y + t1.y; xv[6] = h1.z + t1.z; xv[7] = h1.w + t1.w;

    float s = 0.f;
    #pragma unroll
    for (int j = 0; j < 8; ++j) s += xv[j];
    #pragma unroll
    for (int off = 32; off >= 1; off >>= 1) s += __shfl_xor(s, off, 64);
    float mean = s * (1.f / DMODEL);

    float vs = 0.f;
    #pragma unroll
    for (int j = 0; j < 8; ++j) { float d = xv[j] - mean; vs += d * d; }
    #pragma unroll
    for (int off = 32; off >= 1; off >>= 1) vs += __shfl_xor(vs, off, 64);
    float rstd = rsqrtf(vs * (1.f / DMODEL) + 1e-5f);

    float4 g0 = *(const float4*)(g + lane * 8);
    float4 g1 = *(const float4*)(g + lane * 8 + 4);
    float4 b0 = *(const float4*)(b + lane * 8);
    float4 b1 = *(const float4*)(b + lane * 8 + 4);
    float gg[8] = {g0.x, g0.y, g0.z, g0.w, g1.x, g1.y, g1.z, g1.w};
    float bb[8] = {b0.x, b0.y, b0.z, b0.w, b1.x, b1.y, b1.z, b1.w};

    float outv[8];
    bf16x8 ob;
    #pragma unroll
    for (int j = 0; j < 8; ++j) {
        outv[j] = (xv[j] - mean) * rstd * gg[j] + bb[j];
        ob[j] = (__bf16)outv[j];
    }
    *(float4*)hp       = *(float4*)&outv[0];
    *(float4*)(hp + 4) = *(float4*)&outv[4];
    *(bf16x8*)(hb + (size_t)row * DMODEL + lane * 8) = ob;
}

// ---------------------------------------------------------------------------
// Max-pool pass 1: grid (BATCH, TCHUNK).
// ---------------------------------------------------------------------------
__global__ __launch_bounds__(256)
void pool_p1(const float* __restrict__ hbuf, float* __restrict__ part)
{
    const int bb  = blockIdx.x;
    const int tc  = blockIdx.y;
    const int tid = threadIdx.x;
    const int t0  = tc * (T_SEQ / TCHUNK);
    const float* p = hbuf + ((size_t)bb * T_SEQ + t0) * DMODEL;

    float mx0 = -3.4e38f, mx1 = -3.4e38f;
    for (int t = 0; t < T_SEQ / TCHUNK; ++t) {
        mx0 = fmaxf(mx0, p[(size_t)t * DMODEL + tid]);
        mx1 = fmaxf(mx1, p[(size_t)t * DMODEL + 256 + tid]);
    }
    float* q = part + ((size_t)bb * TCHUNK + tc) * DMODEL;
    q[tid]       = mx0;
    q[tid + 256] = mx1;
}

// ---------------------------------------------------------------------------
// Max-pool pass 2 + classifier + log_softmax. One block per batch item.
// ---------------------------------------------------------------------------
__global__ __launch_bounds__(256)
void pool_p2(const float* __restrict__ part, const float* __restrict__ Wcls,
             const float* __restrict__ bcls, float* __restrict__ out)
{
    __shared__ float pooled[DMODEL];
    __shared__ float logits[8];
    const int bb  = blockIdx.x;
    const int tid = threadIdx.x;

    const float* q = part + (size_t)bb * TCHUNK * DMODEL;
    #pragma unroll
    for (int u = 0; u < 2; ++u) {
        const int d = tid + u * 256;
        float mx = -3.4e38f;
        for (int c = 0; c < TCHUNK; ++c) mx = fmaxf(mx, q[(size_t)c * DMODEL + d]);
        pooled[d] = mx;
    }
    __syncthreads();

    const int cls  = tid >> 5;
    const int lsub = tid & 31;
    const float* wr = Wcls + cls * DMODEL;
    float s = 0.f;
    #pragma unroll
    for (int u = 0; u < 16; ++u) {
        const int d = lsub + u * 32;
        s = fmaf(pooled[d], wr[d], s);
    }
    #pragma unroll
    for (int off = 16; off >= 1; off >>= 1) s += __shfl_xor(s, off, 32);
    if (lsub == 0) logits[cls] = s + bcls[cls];
    __syncthreads();

    if (tid == 0) {
        float mx = logits[0];
        for (int c = 1; c < 8; ++c) mx = fmaxf(mx, logits[c]);
        float se = 0.f;
        for (int c = 0; c < 8; ++c) se += expf(logits[c] - mx);
        float lse = logf(se) + mx;
        for (int c = 0; c < 8; ++c) out[bb * 8 + c] = logits[c] - lse;
    }
}

// ---------------------------------------------------------------------------
extern "C" void kernel_launch(void* const* d_in, const int* in_sizes, int n_in,
                              void* d_out, int out_size, void* d_ws, size_t ws_size,
                              hipStream_t stream)
{
    const float* x    = (const float*)d_in[0];
    const float* Wemb = (const float*)d_in[1];
    const float* bemb = (const float*)d_in[2];
    const float* Wqkv = (const float*)d_in[3];
    const float* bqkv = (const float*)d_in[4];
    const float* Wo   = (const float*)d_in[5];
    const float* bo   = (const float*)d_in[6];
    const float* W1   = (const float*)d_in[7];
    const float* b1f  = (const float*)d_in[8];
    const float* W2   = (const float*)d_in[9];
    const float* b2f  = (const float*)d_in[10];
    const float* g1   = (const float*)d_in[11];
    const float* be1  = (const float*)d_in[12];
    const float* g2   = (const float*)d_in[13];
    const float* be2  = (const float*)d_in[14];
    const float* Wcls = (const float*)d_in[15];
    const float* bcls = (const float*)d_in[16];
    float* out = (float*)d_out;

    // -------- workspace layout --------
    float*  h    = (float*)d_ws;                       // 8000x512 f32
    float*  tmpF = h + (size_t)MROWS * DMODEL;         // 8000x512 f32 (also pool partials)
    __bf16* hb   = (__bf16*)(tmpF + (size_t)MROWS * DMODEL);   // 8000x512
    __bf16* qkvb = hb + (size_t)MROWS * DMODEL;        // 8000x1536
    __bf16* attb = qkvb + (size_t)MROWS * 3 * DMODEL;  // 8000x512
    __bf16* ff1b = qkvb;                               // alias: 8000x2048
    __bf16* xb   = attb + (size_t)MROWS * DMODEL;      // 8000x256
    __bf16* wb   = xb + (size_t)MROWS * 256;
    __bf16* wEmb = wb;
    __bf16* wQKV = wEmb + 512 * 256;
    __bf16* wWo  = wQKV + (size_t)NLAYER * 3 * DMODEL * DMODEL;
    __bf16* wW1  = wWo  + (size_t)NLAYER * DMODEL * DMODEL;
    __bf16* wW2  = wW1  + (size_t)NLAYER * FFDIM * DMODEL;

    dim3 blk(256);

    f2bf<<<dim3(MROWS * 256 / 1024), blk, 0, stream>>>(x, xb);
    f2bf<<<dim3(512 * 256 / 1024), blk, 0, stream>>>(Wemb, wEmb);
    f2bf<<<dim3(NLAYER * 3 * DMODEL * DMODEL / 1024), blk, 0, stream>>>(Wqkv, wQKV);
    f2bf<<<dim3(NLAYER * DMODEL * DMODEL / 1024), blk, 0, stream>>>(Wo, wWo);
    f2bf<<<dim3(NLAYER * FFDIM * DMODEL / 1024), blk, 0, stream>>>(W1, wW1);
    f2bf<<<dim3(NLAYER * DMODEL * FFDIM / 1024), blk, 0, stream>>>(W2, wW2);

    // embed: N=512 -> TM=64, grid (4,125) = 500 blocks
    gemm_bf16<64, true, false, false><<<dim3(4, 125), blk, 0, stream>>>(
        xb, wEmb, bemb, h, nullptr, MROWS, DMODEL, 256);
    add_pe<<<dim3(MROWS * DMODEL / 256), blk, 0, stream>>>(h, hb);

    for (int l = 0; l < NLAYER; ++l) {
        // QKV: N=1536, 756 blocks at TM=128 (enough TLP)
        gemm_bf16<128, false, true, false><<<dim3(12, 63), blk, 0, stream>>>(
            hb, wQKV + (size_t)l * 3 * DMODEL * DMODEL, bqkv + (size_t)l * 3 * DMODEL,
            nullptr, qkvb, MROWS, 3 * DMODEL, DMODEL);
        attn_mfma<<<dim3(512), blk, 0, stream>>>(qkvb, attb);
        // Wo: N=512 -> TM=64
        gemm_bf16<64, true, false, false><<<dim3(4, 125), blk, 0, stream>>>(
            attb, wWo + (size_t)l * DMODEL * DMODEL, bo + (size_t)l * DMODEL,
            tmpF, nullptr, MROWS, DMODEL, DMODEL);
        add_ln<<<dim3(MROWS / 4), blk, 0, stream>>>(
            h, tmpF, g1 + (size_t)l * DMODEL, be1 + (size_t)l * DMODEL, hb);
        // FF1: N=2048, 1008 blocks at TM=128
        gemm_bf16<128, false, true, true><<<dim3(16, 63), blk, 0, stream>>>(
            hb, wW1 + (size_t)l * FFDIM * DMODEL, b1f + (size_t)l * FFDIM,
            nullptr, ff1b, MROWS, FFDIM, DMODEL);
        // FF2: N=512 -> TM=64, grid 500 blocks
        gemm_bf16<64, true, false, false><<<dim3(4, 125), blk, 0, stream>>>(
            ff1b, wW2 + (size_t)l * DMODEL * FFDIM, b2f + (size_t)l * DMODEL,
            tmpF, nullptr, MROWS, DMODEL, FFDIM);
        add_ln<<<dim3(MROWS / 4), blk, 0, stream>>>(
            h, tmpF, g2 + (size_t)l * DMODEL, be2 + (size_t)l * DMODEL, hb);
    }

    pool_p1<<<dim3(BATCH, TCHUNK), blk, 0, stream>>>(h, tmpF);
    pool_p2<<<dim3(BATCH), blk, 0, stream>>>(tmpF, Wcls, bcls, out);
}

// Round 7
// 695.874 us; speedup vs baseline: 1.3180x; 1.2512x over previous
//
#include <hip/hip_runtime.h>
#include <math.h>

#define T_SEQ   1000
#define BATCH   8
#define DMODEL  512
#define NHEAD   8
#define DHEAD   64
#define FFDIM   2048
#define NLAYER  4
#define MROWS   (BATCH * T_SEQ)   // 8000
#define TCHUNK  25                // pooling pass-1 chunks (40 t each)

typedef __bf16 bf16x8 __attribute__((ext_vector_type(8)));
typedef __bf16 bf16x4 __attribute__((ext_vector_type(4)));
typedef float  f32x4  __attribute__((ext_vector_type(4)));
typedef float  f32x16 __attribute__((ext_vector_type(16)));

#define GL2LDS(g, l) \
    __builtin_amdgcn_global_load_lds((const __attribute__((address_space(1))) void*)(g), \
                                     (__attribute__((address_space(3))) void*)(l), 16, 0, 0)

// ---------------------------------------------------------------------------
// fp32 -> bf16 convert, 4 elems/thread.
// ---------------------------------------------------------------------------
__global__ __launch_bounds__(256)
void f2bf(const float* __restrict__ in, __bf16* __restrict__ out)
{
    int i = (blockIdx.x * 256 + threadIdx.x) * 4;
    float4 v = *(const float4*)(in + i);
    bf16x4 o;
    o[0] = (__bf16)v.x; o[1] = (__bf16)v.y; o[2] = (__bf16)v.z; o[3] = (__bf16)v.w;
    *(bf16x4*)(out + i) = o;
}

// ---------------------------------------------------------------------------
// bf16 MFMA GEMM: C(MxN) = A(MxK) @ B(NxK)^T + bias.   M % 64 == 0.
// 64x128 tile, BK=64, 4 waves (2x2), 16x16x32 MFMA.
// T2: st-16-byte XOR swizzle (col ^= (row&7)<<4). global_load_lds writes
// linearly, so the GLOBAL source is inverse-swizzled and the ds_read applies
// the same XOR (rule #21: both-sides-or-neither).
// T4: 3 LDS buffers, stage(t+2) issued before compute(t), counted
// s_waitcnt vmcnt(6) (tile t+1's 6 loads done, t+2's stay in flight) +
// raw s_barrier + sched_barrier(0). Never drains vmcnt to 0 mid-loop.
// ---------------------------------------------------------------------------
template<bool WF32, bool WBF16, bool RELU>
__global__ __launch_bounds__(256)
void gemm_bf16(const __bf16* __restrict__ A, const __bf16* __restrict__ B,
               const float* __restrict__ bias, float* __restrict__ Cf,
               __bf16* __restrict__ Cb, int M, int N, int K)
{
    __shared__ __align__(16) __bf16 As[3][64 * 64];    // 3 x 8 KB
    __shared__ __align__(16) __bf16 Bs[3][128 * 64];   // 3 x 16 KB

    const int tid  = threadIdx.x;
    const int lane = tid & 63;
    const int w    = tid >> 6;
    const int wr   = w >> 1, wc = w & 1;
    const int row0 = blockIdx.y * 64;
    const int col0 = blockIdx.x * 128;

    // staging: linear LDS dest, inverse-swizzled global source
    size_t aoffg[2], boffg[4];
    int    ldso[4];
    #pragma unroll
    for (int p = 0; p < 4; ++p) {
        const int bo = p * 4096 + tid * 16;
        const int r  = bo >> 7;                         // tile row
        const int cs = (bo & 127) ^ ((r & 7) << 4);     // inverse-swizzled col byte
        if (p < 2) aoffg[p] = (size_t)(row0 + r) * K * 2 + cs;
        boffg[p] = (size_t)(col0 + r) * K * 2 + cs;
        ldso[p]  = bo;
    }

    f32x4 acc[2][4];
    #pragma unroll
    for (int m = 0; m < 2; ++m)
        #pragma unroll
        for (int n = 0; n < 4; ++n) acc[m][n] = (f32x4)0.f;

    const char* gA = (const char*)A;
    const char* gB = (const char*)B;
    const int nt = K >> 6;

    auto STAGE = [&](int tt, int buf) {
        const size_t kb = (size_t)tt << 7;              // tt*64 elems * 2B
        char* lA = (char*)As[buf];
        char* lB = (char*)Bs[buf];
        #pragma unroll
        for (int p = 0; p < 2; ++p) GL2LDS(gA + aoffg[p] + kb, lA + ldso[p]);
        #pragma unroll
        for (int p = 0; p < 4; ++p) GL2LDS(gB + boffg[p] + kb, lB + ldso[p]);
    };

    // prologue: tiles 0,1 in flight; wait for tile 0 only
    STAGE(0, 0);
    STAGE(1, 1);
    asm volatile("s_waitcnt vmcnt(6)" ::: "memory");
    __builtin_amdgcn_s_barrier();
    __builtin_amdgcn_sched_barrier(0);

    int bc = 0, bn = 2;
    for (int t = 0; t < nt; ++t) {
        if (t + 2 < nt) STAGE(t + 2, bn);
        const char* as = (const char*)As[bc];
        const char* bs = (const char*)Bs[bc];
        #pragma unroll
        for (int ks = 0; ks < 2; ++ks) {
            bf16x8 af[2], bfr[4];
            const int cb = ks * 64 + (lane >> 4) * 16;
            #pragma unroll
            for (int m = 0; m < 2; ++m) {
                const int rr = wr * 32 + m * 16 + (lane & 15);
                af[m] = *(const bf16x8*)(as + rr * 128 + (cb ^ ((rr & 7) << 4)));
            }
            #pragma unroll
            for (int n = 0; n < 4; ++n) {
                const int rr = wc * 64 + n * 16 + (lane & 15);
                bfr[n] = *(const bf16x8*)(bs + rr * 128 + (cb ^ ((rr & 7) << 4)));
            }
            #pragma unroll
            for (int m = 0; m < 2; ++m)
                #pragma unroll
                for (int n = 0; n < 4; ++n)
                    acc[m][n] = __builtin_amdgcn_mfma_f32_16x16x32_bf16(af[m], bfr[n], acc[m][n], 0, 0, 0);
        }
        if (t + 2 < nt) { asm volatile("s_waitcnt vmcnt(6)" ::: "memory"); }
        else            { asm volatile("s_waitcnt vmcnt(0)" ::: "memory"); }
        __builtin_amdgcn_s_barrier();
        __builtin_amdgcn_sched_barrier(0);
        bc = bc + 1; if (bc == 3) bc = 0;
        bn = bn + 1; if (bn == 3) bn = 0;
    }

    const int crow = (lane >> 4) * 4;
    const int ccol = lane & 15;
    #pragma unroll
    for (int n = 0; n < 4; ++n) {
        const int gc = col0 + wc * 64 + n * 16 + ccol;
        const float bv = bias[gc];
        #pragma unroll
        for (int m = 0; m < 2; ++m) {
            const int gr0 = row0 + wr * 32 + m * 16 + crow;
            #pragma unroll
            for (int r = 0; r < 4; ++r) {
                const int gr = gr0 + r;
                float v = acc[m][n][r] + bv;
                if (RELU) v = fmaxf(v, 0.f);
                if (WF32)  Cf[(size_t)gr * N + gc] = v;
                if (WBF16) Cb[(size_t)gr * N + gc] = (__bf16)v;
            }
        }
    }
}

// ---------------------------------------------------------------------------
// Add sinusoidal PE in place (fp32) + write bf16 shadow.
// ---------------------------------------------------------------------------
__global__ __launch_bounds__(256)
void add_pe(float* __restrict__ hbuf, __bf16* __restrict__ hb)
{
    int idx = blockIdx.x * 256 + threadIdx.x;
    int d   = idx & (DMODEL - 1);
    int t   = (idx >> 9) % T_SEQ;
    float freq = expf((float)(d & ~1) * (-9.210340371976184f / (float)DMODEL));
    float ang  = (float)t * freq;
    float pe   = (d & 1) ? cosf(ang) : sinf(ang);
    float v = hbuf[idx] + pe;
    hbuf[idx] = v;
    hb[idx]   = (__bf16)v;
}

// ---------------------------------------------------------------------------
// MFMA flash attention over the band, 32x32x16, swapped-operand structure.
// ---------------------------------------------------------------------------
__global__ __launch_bounds__(256)
void attn_mfma(const __bf16* __restrict__ qkv, __bf16* __restrict__ o)
{
    const int wv   = (blockIdx.x << 2) + (threadIdx.x >> 6);
    const int lane = threadIdx.x & 63;
    const int qt   = wv & 31;
    const int hh   = (wv >> 5) & 7;
    const int b    = wv >> 8;
    const int qb   = qt * 32;
    const int half = lane >> 5;
    const int ql   = lane & 31;
    const int i    = qb + ql;
    const int iq   = (i < T_SEQ) ? i : (T_SEQ - 1);

    const int RS = 3 * DMODEL;
    const __bf16* Q = qkv + (size_t)b * T_SEQ * RS + hh * DHEAD;
    const __bf16* K = Q + DMODEL;
    const __bf16* V = Q + 2 * DMODEL;

    bf16x8 qf[4];
    {
        const __bf16* qrow = Q + (size_t)iq * RS + half * 8;
        #pragma unroll
        for (int ds = 0; ds < 4; ++ds)
            qf[ds] = *(const bf16x8*)(qrow + ds * 16);
    }

    const int w = 25 * (hh + 1);
    const int kb_lo = (qb - w > 0 ? qb - w : 0) & ~31;
    const int kb_hi = (qb + 31 + w < T_SEQ - 1) ? (qb + 31 + w) : (T_SEQ - 1);
    const int  spanv = (2 * w < T_SEQ - 1 - i + w) ? 2 * w : (T_SEQ - 1 - i + w);
    const unsigned span = (unsigned)spanv;
    const float C2 = 0.125f * 1.44269504089f;

    float m2 = -1e9f, l = 0.f;
    f32x16 oa0 = (f32x16)0.f, oa1 = (f32x16)0.f;

    for (int kb = kb_lo; kb <= kb_hi; kb += 32) {
        f32x16 sv = (f32x16)0.f;
        {
            int krow = kb + ql; if (krow > T_SEQ - 1) krow = T_SEQ - 1;
            const __bf16* kr = K + (size_t)krow * RS + half * 8;
            #pragma unroll
            for (int ds = 0; ds < 4; ++ds) {
                bf16x8 kf = *(const bf16x8*)(kr + ds * 16);
                sv = __builtin_amdgcn_mfma_f32_32x32x16_bf16(kf, qf[ds], sv, 0, 0, 0);
            }
        }

        const int base = kb - i + w;
        float s2[16];
        #pragma unroll
        for (int r = 0; r < 16; ++r) {
            const int kr = (r & 3) + 8 * (r >> 2) + 4 * half;
            const unsigned jrel = (unsigned)(base + kr);
            s2[r] = (jrel <= span) ? sv[r] * C2 : -1e9f;
        }

        float mx = s2[0];
        #pragma unroll
        for (int r = 1; r < 16; ++r) mx = fmaxf(mx, s2[r]);
        mx = fmaxf(mx, __shfl_xor(mx, 32, 64));

        if (!__all(mx <= m2 + 8.0f)) {
            const float mnew  = fmaxf(m2, mx);
            const float scale = exp2f(m2 - mnew);
            m2 = mnew;
            l *= scale;
            #pragma unroll
            for (int r = 0; r < 16; ++r) {
                const int qsrc = (r & 3) + 8 * (r >> 2) + 4 * half;
                const float sc = __shfl(scale, qsrc, 64);
                oa0[r] *= sc;
                oa1[r] *= sc;
            }
        }

        float p[16];
        float ps = 0.f;
        #pragma unroll
        for (int r = 0; r < 16; ++r) { p[r] = exp2f(s2[r] - m2); ps += p[r]; }
        ps += __shfl_xor(ps, 32, 64);
        l += ps;

        unsigned pk[8];
        #pragma unroll
        for (int t = 0; t < 8; ++t) {
            union { unsigned u; __bf16 h[2]; } cv;
            cv.h[0] = (__bf16)p[2 * t];
            cv.h[1] = (__bf16)p[2 * t + 1];
            pk[t] = cv.u;
        }
        unsigned y[8];
        #pragma unroll
        for (int t = 0; t < 8; ++t)
            y[t] = (unsigned)__shfl_xor((int)pk[t], 32, 64);

        union { unsigned u[4]; bf16x8 v; } pa0, pa1;
        if (half == 0) {
            pa0.u[0] = pk[0]; pa0.u[1] = pk[1]; pa0.u[2] = y[0];  pa0.u[3] = y[1];
            pa1.u[0] = pk[4]; pa1.u[1] = pk[5]; pa1.u[2] = y[4];  pa1.u[3] = y[5];
        } else {
            pa0.u[0] = y[2];  pa0.u[1] = y[3];  pa0.u[2] = pk[2]; pa0.u[3] = pk[3];
            pa1.u[0] = y[6];  pa1.u[1] = y[7];  pa1.u[2] = pk[6]; pa1.u[3] = pk[7];
        }

        #pragma unroll
        for (int ks = 0; ks < 2; ++ks) {
            const int R0 = kb + ks * 16 + half * 8;
            #pragma unroll
            for (int dh = 0; dh < 2; ++dh) {
                bf16x8 vf;
                const __bf16* vcol = V + dh * 32 + ql;
                #pragma unroll
                for (int j = 0; j < 8; ++j) {
                    int rr = R0 + j; if (rr > T_SEQ - 1) rr = T_SEQ - 1;
                    vf[j] = vcol[(size_t)rr * RS];
                }
                if (dh == 0)
                    oa0 = __builtin_amdgcn_mfma_f32_32x32x16_bf16(ks ? pa1.v : pa0.v, vf, oa0, 0, 0, 0);
                else
                    oa1 = __builtin_amdgcn_mfma_f32_32x32x16_bf16(ks ? pa1.v : pa0.v, vf, oa1, 0, 0, 0);
            }
        }
    }

    const float rinv = 1.f / l;
    __bf16* ob = o + ((size_t)b * T_SEQ) * DMODEL + hh * DHEAD;
    #pragma unroll
    for (int r = 0; r < 16; ++r) {
        const int q   = (r & 3) + 8 * (r >> 2) + 4 * half;
        const int row = qb + q;
        const float ri = __shfl(rinv, q, 64);
        if (row < T_SEQ) {
            ob[(size_t)row * DMODEL + ql]      = (__bf16)(oa0[r] * ri);
            ob[(size_t)row * DMODEL + 32 + ql] = (__bf16)(oa1[r] * ri);
        }
    }
}

// ---------------------------------------------------------------------------
// h = LayerNorm(h + t) * g + b (fp32 residual stream) + bf16 shadow.
// ---------------------------------------------------------------------------
__global__ __launch_bounds__(256)
void add_ln(float* __restrict__ hbuf, const float* __restrict__ tbuf,
            const float* __restrict__ g, const float* __restrict__ b,
            __bf16* __restrict__ hb)
{
    const int row  = blockIdx.x * 4 + (threadIdx.x >> 6);
    const int lane = threadIdx.x & 63;
    float*       hp = hbuf + (size_t)row * DMODEL + lane * 8;
    const float* tp = tbuf + (size_t)row * DMODEL + lane * 8;

    float xv[8];
    float4 h0 = *(const float4*)hp;   float4 h1 = *(const float4*)(hp + 4);
    float4 t0 = *(const float4*)tp;   float4 t1 = *(const float4*)(tp + 4);
    xv[0] = h0.x + t0.x; xv[1] = h0.y + t0.y; xv[2] = h0.z + t0.z; xv[3] = h0.w + t0.w;
    xv[4] = h1.x + t1.x; xv[5] = h1.y + t1.y; xv[6] = h1.z + t1.z; xv[7] = h1.w + t1.w;

    float s = 0.f;
    #pragma unroll
    for (int j = 0; j < 8; ++j) s += xv[j];
    #pragma unroll
    for (int off = 32; off >= 1; off >>= 1) s += __shfl_xor(s, off, 64);
    float mean = s * (1.f / DMODEL);

    float vs = 0.f;
    #pragma unroll
    for (int j = 0; j < 8; ++j) { float d = xv[j] - mean; vs += d * d; }
    #pragma unroll
    for (int off = 32; off >= 1; off >>= 1) vs += __shfl_xor(vs, off, 64);
    float rstd = rsqrtf(vs * (1.f / DMODEL) + 1e-5f);

    float4 g0 = *(const float4*)(g + lane * 8);
    float4 g1 = *(const float4*)(g + lane * 8 + 4);
    float4 b0 = *(const float4*)(b + lane * 8);
    float4 b1 = *(const float4*)(b + lane * 8 + 4);
    float gg[8] = {g0.x, g0.y, g0.z, g0.w, g1.x, g1.y, g1.z, g1.w};
    float bb[8] = {b0.x, b0.y, b0.z, b0.w, b1.x, b1.y, b1.z, b1.w};

    float outv[8];
    bf16x8 ob;
    #pragma unroll
    for (int j = 0; j < 8; ++j) {
        outv[j] = (xv[j] - mean) * rstd * gg[j] + bb[j];
        ob[j] = (__bf16)outv[j];
    }
    *(float4*)hp       = *(float4*)&outv[0];
    *(float4*)(hp + 4) = *(float4*)&outv[4];
    *(bf16x8*)(hb + (size_t)row * DMODEL + lane * 8) = ob;
}

// ---------------------------------------------------------------------------
// Max-pool pass 1: grid (BATCH, TCHUNK).
// ---------------------------------------------------------------------------
__global__ __launch_bounds__(256)
void pool_p1(const float* __restrict__ hbuf, float* __restrict__ part)
{
    const int bb  = blockIdx.x;
    const int tc  = blockIdx.y;
    const int tid = threadIdx.x;
    const int t0  = tc * (T_SEQ / TCHUNK);
    const float* p = hbuf + ((size_t)bb * T_SEQ + t0) * DMODEL;

    float mx0 = -3.4e38f, mx1 = -3.4e38f;
    for (int t = 0; t < T_SEQ / TCHUNK; ++t) {
        mx0 = fmaxf(mx0, p[(size_t)t * DMODEL + tid]);
        mx1 = fmaxf(mx1, p[(size_t)t * DMODEL + 256 + tid]);
    }
    float* q = part + ((size_t)bb * TCHUNK + tc) * DMODEL;
    q[tid]       = mx0;
    q[tid + 256] = mx1;
}

// ---------------------------------------------------------------------------
// Max-pool pass 2 + classifier + log_softmax. One block per batch item.
// ---------------------------------------------------------------------------
__global__ __launch_bounds__(256)
void pool_p2(const float* __restrict__ part, const float* __restrict__ Wcls,
             const float* __restrict__ bcls, float* __restrict__ out)
{
    __shared__ float pooled[DMODEL];
    __shared__ float logits[8];
    const int bb  = blockIdx.x;
    const int tid = threadIdx.x;

    const float* q = part + (size_t)bb * TCHUNK * DMODEL;
    #pragma unroll
    for (int u = 0; u < 2; ++u) {
        const int d = tid + u * 256;
        float mx = -3.4e38f;
        for (int c = 0; c < TCHUNK; ++c) mx = fmaxf(mx, q[(size_t)c * DMODEL + d]);
        pooled[d] = mx;
    }
    __syncthreads();

    const int cls  = tid >> 5;
    const int lsub = tid & 31;
    const float* wr = Wcls + cls * DMODEL;
    float s = 0.f;
    #pragma unroll
    for (int u = 0; u < 16; ++u) {
        const int d = lsub + u * 32;
        s = fmaf(pooled[d], wr[d], s);
    }
    #pragma unroll
    for (int off = 16; off >= 1; off >>= 1) s += __shfl_xor(s, off, 32);
    if (lsub == 0) logits[cls] = s + bcls[cls];
    __syncthreads();

    if (tid == 0) {
        float mx = logits[0];
        for (int c = 1; c < 8; ++c) mx = fmaxf(mx, logits[c]);
        float se = 0.f;
        for (int c = 0; c < 8; ++c) se += expf(logits[c] - mx);
        float lse = logf(se) + mx;
        for (int c = 0; c < 8; ++c) out[bb * 8 + c] = logits[c] - lse;
    }
}

// ---------------------------------------------------------------------------
extern "C" void kernel_launch(void* const* d_in, const int* in_sizes, int n_in,
                              void* d_out, int out_size, void* d_ws, size_t ws_size,
                              hipStream_t stream)
{
    const float* x    = (const float*)d_in[0];
    const float* Wemb = (const float*)d_in[1];
    const float* bemb = (const float*)d_in[2];
    const float* Wqkv = (const float*)d_in[3];
    const float* bqkv = (const float*)d_in[4];
    const float* Wo   = (const float*)d_in[5];
    const float* bo   = (const float*)d_in[6];
    const float* W1   = (const float*)d_in[7];
    const float* b1f  = (const float*)d_in[8];
    const float* W2   = (const float*)d_in[9];
    const float* b2f  = (const float*)d_in[10];
    const float* g1   = (const float*)d_in[11];
    const float* be1  = (const float*)d_in[12];
    const float* g2   = (const float*)d_in[13];
    const float* be2  = (const float*)d_in[14];
    const float* Wcls = (const float*)d_in[15];
    const float* bcls = (const float*)d_in[16];
    float* out = (float*)d_out;

    // -------- workspace layout --------
    float*  h    = (float*)d_ws;                       // 8000x512 f32
    float*  tmpF = h + (size_t)MROWS * DMODEL;         // 8000x512 f32 (also pool partials)
    __bf16* hb   = (__bf16*)(tmpF + (size_t)MROWS * DMODEL);   // 8000x512
    __bf16* qkvb = hb + (size_t)MROWS * DMODEL;        // 8000x1536
    __bf16* attb = qkvb + (size_t)MROWS * 3 * DMODEL;  // 8000x512
    __bf16* ff1b = qkvb;                               // alias: 8000x2048
    __bf16* xb   = attb + (size_t)MROWS * DMODEL;      // 8000x256
    __bf16* wb   = xb + (size_t)MROWS * 256;
    __bf16* wEmb = wb;
    __bf16* wQKV = wEmb + 512 * 256;
    __bf16* wWo  = wQKV + (size_t)NLAYER * 3 * DMODEL * DMODEL;
    __bf16* wW1  = wWo  + (size_t)NLAYER * DMODEL * DMODEL;
    __bf16* wW2  = wW1  + (size_t)NLAYER * FFDIM * DMODEL;

    dim3 blk(256);

    f2bf<<<dim3(MROWS * 256 / 1024), blk, 0, stream>>>(x, xb);
    f2bf<<<dim3(512 * 256 / 1024), blk, 0, stream>>>(Wemb, wEmb);
    f2bf<<<dim3(NLAYER * 3 * DMODEL * DMODEL / 1024), blk, 0, stream>>>(Wqkv, wQKV);
    f2bf<<<dim3(NLAYER * DMODEL * DMODEL / 1024), blk, 0, stream>>>(Wo, wWo);
    f2bf<<<dim3(NLAYER * FFDIM * DMODEL / 1024), blk, 0, stream>>>(W1, wW1);
    f2bf<<<dim3(NLAYER * DMODEL * FFDIM / 1024), blk, 0, stream>>>(W2, wW2);

    // embed: grid (4,125) = 500 blocks
    gemm_bf16<true, false, false><<<dim3(4, 125), blk, 0, stream>>>(
        xb, wEmb, bemb, h, nullptr, MROWS, DMODEL, 256);
    add_pe<<<dim3(MROWS * DMODEL / 256), blk, 0, stream>>>(h, hb);

    for (int l = 0; l < NLAYER; ++l) {
        // QKV: N=1536 -> grid (12,125) = 1500 blocks
        gemm_bf16<false, true, false><<<dim3(12, 125), blk, 0, stream>>>(
            hb, wQKV + (size_t)l * 3 * DMODEL * DMODEL, bqkv + (size_t)l * 3 * DMODEL,
            nullptr, qkvb, MROWS, 3 * DMODEL, DMODEL);
        attn_mfma<<<dim3(512), blk, 0, stream>>>(qkvb, attb);
        // Wo: N=512 -> grid (4,125)
        gemm_bf16<true, false, false><<<dim3(4, 125), blk, 0, stream>>>(
            attb, wWo + (size_t)l * DMODEL * DMODEL, bo + (size_t)l * DMODEL,
            tmpF, nullptr, MROWS, DMODEL, DMODEL);
        add_ln<<<dim3(MROWS / 4), blk, 0, stream>>>(
            h, tmpF, g1 + (size_t)l * DMODEL, be1 + (size_t)l * DMODEL, hb);
        // FF1: N=2048 -> grid (16,125) = 2000 blocks
        gemm_bf16<false, true, true><<<dim3(16, 125), blk, 0, stream>>>(
            hb, wW1 + (size_t)l * FFDIM * DMODEL, b1f + (size_t)l * FFDIM,
            nullptr, ff1b, MROWS, FFDIM, DMODEL);
        // FF2: N=512, K=2048 -> grid (4,125)
        gemm_bf16<true, false, false><<<dim3(4, 125), blk, 0, stream>>>(
            ff1b, wW2 + (size_t)l * DMODEL * FFDIM, b2f + (size_t)l * DMODEL,
            tmpF, nullptr, MROWS, DMODEL, FFDIM);
        add_ln<<<dim3(MROWS / 4), blk, 0, stream>>>(
            h, tmpF, g2 + (size_t)l * DMODEL, be2 + (size_t)l * DMODEL, hb);
    }

    pool_p1<<<dim3(BATCH, TCHUNK), blk, 0, stream>>>(h, tmpF);
    pool_p2<<<dim3(BATCH), blk, 0, stream>>>(tmpF, Wcls, bcls, out);
}

// Round 8
// 674.610 us; speedup vs baseline: 1.3596x; 1.0315x over previous
//
#include <hip/hip_runtime.h>
#include <math.h>

#define T_SEQ   1000
#define BATCH   8
#define DMODEL  512
#define NHEAD   8
#define DHEAD   64
#define FFDIM   2048
#define NLAYER  4
#define MROWS   (BATCH * T_SEQ)   // 8000
#define TCHUNK  25                // pooling pass-1 chunks (40 t each)

typedef __bf16 bf16x8 __attribute__((ext_vector_type(8)));
typedef __bf16 bf16x4 __attribute__((ext_vector_type(4)));
typedef float  f32x4  __attribute__((ext_vector_type(4)));
typedef float  f32x16 __attribute__((ext_vector_type(16)));

#define GL2LDS(g, l) \
    __builtin_amdgcn_global_load_lds((const __attribute__((address_space(1))) void*)(g), \
                                     (__attribute__((address_space(3))) void*)(l), 16, 0, 0)

// ---------------------------------------------------------------------------
// fp32 -> bf16 convert, 4 elems/thread.
// ---------------------------------------------------------------------------
__global__ __launch_bounds__(256)
void f2bf(const float* __restrict__ in, __bf16* __restrict__ out)
{
    int i = (blockIdx.x * 256 + threadIdx.x) * 4;
    float4 v = *(const float4*)(in + i);
    bf16x4 o;
    o[0] = (__bf16)v.x; o[1] = (__bf16)v.y; o[2] = (__bf16)v.z; o[3] = (__bf16)v.w;
    *(bf16x4*)(out + i) = o;
}

// ---------------------------------------------------------------------------
// bf16 MFMA GEMM: C(MxN) = A(MxK) @ B(NxK)^T + bias.   M % 64 == 0.
// 64x128 tile, BK=64, 4 waves (2x2), 16x16x32 MFMA.
// T2 swizzle (both-sides: inverse-swz global src + swz ds_read), T4 counted
// vmcnt(6) 3-buffer pipeline, T5 setprio around the MFMA cluster.
// PE: fuse sinusoidal positional encoding into the epilogue (embed only,
// assumes N == DMODEL so gc == d).
// ---------------------------------------------------------------------------
template<bool WF32, bool WBF16, bool RELU, bool PE>
__global__ __launch_bounds__(256)
void gemm_bf16(const __bf16* __restrict__ A, const __bf16* __restrict__ B,
               const float* __restrict__ bias, float* __restrict__ Cf,
               __bf16* __restrict__ Cb, int M, int N, int K)
{
    __shared__ __align__(16) __bf16 As[3][64 * 64];    // 3 x 8 KB
    __shared__ __align__(16) __bf16 Bs[3][128 * 64];   // 3 x 16 KB

    const int tid  = threadIdx.x;
    const int lane = tid & 63;
    const int w    = tid >> 6;
    const int wr   = w >> 1, wc = w & 1;
    const int row0 = blockIdx.y * 64;
    const int col0 = blockIdx.x * 128;

    // staging: linear LDS dest, inverse-swizzled global source (rule #21)
    size_t aoffg[2], boffg[4];
    int    ldso[4];
    #pragma unroll
    for (int p = 0; p < 4; ++p) {
        const int bo = p * 4096 + tid * 16;
        const int r  = bo >> 7;
        const int cs = (bo & 127) ^ ((r & 7) << 4);
        if (p < 2) aoffg[p] = (size_t)(row0 + r) * K * 2 + cs;
        boffg[p] = (size_t)(col0 + r) * K * 2 + cs;
        ldso[p]  = bo;
    }

    f32x4 acc[2][4];
    #pragma unroll
    for (int m = 0; m < 2; ++m)
        #pragma unroll
        for (int n = 0; n < 4; ++n) acc[m][n] = (f32x4)0.f;

    const char* gA = (const char*)A;
    const char* gB = (const char*)B;
    const int nt = K >> 6;

    auto STAGE = [&](int tt, int buf) {
        const size_t kb = (size_t)tt << 7;
        char* lA = (char*)As[buf];
        char* lB = (char*)Bs[buf];
        #pragma unroll
        for (int p = 0; p < 2; ++p) GL2LDS(gA + aoffg[p] + kb, lA + ldso[p]);
        #pragma unroll
        for (int p = 0; p < 4; ++p) GL2LDS(gB + boffg[p] + kb, lB + ldso[p]);
    };

    STAGE(0, 0);
    STAGE(1, 1);
    asm volatile("s_waitcnt vmcnt(6)" ::: "memory");
    __builtin_amdgcn_s_barrier();
    __builtin_amdgcn_sched_barrier(0);

    int bc = 0, bn = 2;
    for (int t = 0; t < nt; ++t) {
        if (t + 2 < nt) STAGE(t + 2, bn);
        const char* as = (const char*)As[bc];
        const char* bs = (const char*)Bs[bc];
        __builtin_amdgcn_s_setprio(1);
        #pragma unroll
        for (int ks = 0; ks < 2; ++ks) {
            bf16x8 af[2], bfr[4];
            const int cb = ks * 64 + (lane >> 4) * 16;
            #pragma unroll
            for (int m = 0; m < 2; ++m) {
                const int rr = wr * 32 + m * 16 + (lane & 15);
                af[m] = *(const bf16x8*)(as + rr * 128 + (cb ^ ((rr & 7) << 4)));
            }
            #pragma unroll
            for (int n = 0; n < 4; ++n) {
                const int rr = wc * 64 + n * 16 + (lane & 15);
                bfr[n] = *(const bf16x8*)(bs + rr * 128 + (cb ^ ((rr & 7) << 4)));
            }
            #pragma unroll
            for (int m = 0; m < 2; ++m)
                #pragma unroll
                for (int n = 0; n < 4; ++n)
                    acc[m][n] = __builtin_amdgcn_mfma_f32_16x16x32_bf16(af[m], bfr[n], acc[m][n], 0, 0, 0);
        }
        __builtin_amdgcn_s_setprio(0);
        if (t + 2 < nt) { asm volatile("s_waitcnt vmcnt(6)" ::: "memory"); }
        else            { asm volatile("s_waitcnt vmcnt(0)" ::: "memory"); }
        __builtin_amdgcn_s_barrier();
        __builtin_amdgcn_sched_barrier(0);
        bc = bc + 1; if (bc == 3) bc = 0;
        bn = bn + 1; if (bn == 3) bn = 0;
    }

    const int crow = (lane >> 4) * 4;
    const int ccol = lane & 15;
    #pragma unroll
    for (int n = 0; n < 4; ++n) {
        const int gc = col0 + wc * 64 + n * 16 + ccol;
        const float bv = bias[gc];
        float freq = 0.f;
        if (PE) freq = __expf((float)(gc & ~1) * (-9.210340371976184f / (float)DMODEL));
        #pragma unroll
        for (int m = 0; m < 2; ++m) {
            const int gr0 = row0 + wr * 32 + m * 16 + crow;
            #pragma unroll
            for (int r = 0; r < 4; ++r) {
                const int gr = gr0 + r;
                float v = acc[m][n][r] + bv;
                if (PE) {
                    const int tt = gr % T_SEQ;
                    const float ang = (float)tt * freq;
                    v += (gc & 1) ? __cosf(ang) : __sinf(ang);
                }
                if (RELU) v = fmaxf(v, 0.f);
                if (WF32)  Cf[(size_t)gr * N + gc] = v;
                if (WBF16) Cb[(size_t)gr * N + gc] = (__bf16)v;
            }
        }
    }
}

// ---------------------------------------------------------------------------
// MFMA flash attention over the band, 32x32x16, swapped-operand structure.
// ---------------------------------------------------------------------------
__global__ __launch_bounds__(256)
void attn_mfma(const __bf16* __restrict__ qkv, __bf16* __restrict__ o)
{
    const int wv   = (blockIdx.x << 2) + (threadIdx.x >> 6);
    const int lane = threadIdx.x & 63;
    const int qt   = wv & 31;
    const int hh   = (wv >> 5) & 7;
    const int b    = wv >> 8;
    const int qb   = qt * 32;
    const int half = lane >> 5;
    const int ql   = lane & 31;
    const int i    = qb + ql;
    const int iq   = (i < T_SEQ) ? i : (T_SEQ - 1);

    const int RS = 3 * DMODEL;
    const __bf16* Q = qkv + (size_t)b * T_SEQ * RS + hh * DHEAD;
    const __bf16* K = Q + DMODEL;
    const __bf16* V = Q + 2 * DMODEL;

    bf16x8 qf[4];
    {
        const __bf16* qrow = Q + (size_t)iq * RS + half * 8;
        #pragma unroll
        for (int ds = 0; ds < 4; ++ds)
            qf[ds] = *(const bf16x8*)(qrow + ds * 16);
    }

    const int w = 25 * (hh + 1);
    const int kb_lo = (qb - w > 0 ? qb - w : 0) & ~31;
    const int kb_hi = (qb + 31 + w < T_SEQ - 1) ? (qb + 31 + w) : (T_SEQ - 1);
    const int  spanv = (2 * w < T_SEQ - 1 - i + w) ? 2 * w : (T_SEQ - 1 - i + w);
    const unsigned span = (unsigned)spanv;
    const float C2 = 0.125f * 1.44269504089f;

    float m2 = -1e9f, l = 0.f;
    f32x16 oa0 = (f32x16)0.f, oa1 = (f32x16)0.f;

    for (int kb = kb_lo; kb <= kb_hi; kb += 32) {
        f32x16 sv = (f32x16)0.f;
        {
            int krow = kb + ql; if (krow > T_SEQ - 1) krow = T_SEQ - 1;
            const __bf16* kr = K + (size_t)krow * RS + half * 8;
            #pragma unroll
            for (int ds = 0; ds < 4; ++ds) {
                bf16x8 kf = *(const bf16x8*)(kr + ds * 16);
                sv = __builtin_amdgcn_mfma_f32_32x32x16_bf16(kf, qf[ds], sv, 0, 0, 0);
            }
        }

        const int base = kb - i + w;
        float s2[16];
        #pragma unroll
        for (int r = 0; r < 16; ++r) {
            const int kr = (r & 3) + 8 * (r >> 2) + 4 * half;
            const unsigned jrel = (unsigned)(base + kr);
            s2[r] = (jrel <= span) ? sv[r] * C2 : -1e9f;
        }

        float mx = s2[0];
        #pragma unroll
        for (int r = 1; r < 16; ++r) mx = fmaxf(mx, s2[r]);
        mx = fmaxf(mx, __shfl_xor(mx, 32, 64));

        if (!__all(mx <= m2 + 8.0f)) {
            const float mnew  = fmaxf(m2, mx);
            const float scale = exp2f(m2 - mnew);
            m2 = mnew;
            l *= scale;
            #pragma unroll
            for (int r = 0; r < 16; ++r) {
                const int qsrc = (r & 3) + 8 * (r >> 2) + 4 * half;
                const float sc = __shfl(scale, qsrc, 64);
                oa0[r] *= sc;
                oa1[r] *= sc;
            }
        }

        float p[16];
        float ps = 0.f;
        #pragma unroll
        for (int r = 0; r < 16; ++r) { p[r] = exp2f(s2[r] - m2); ps += p[r]; }
        ps += __shfl_xor(ps, 32, 64);
        l += ps;

        unsigned pk[8];
        #pragma unroll
        for (int t = 0; t < 8; ++t) {
            union { unsigned u; __bf16 h[2]; } cv;
            cv.h[0] = (__bf16)p[2 * t];
            cv.h[1] = (__bf16)p[2 * t + 1];
            pk[t] = cv.u;
        }
        unsigned y[8];
        #pragma unroll
        for (int t = 0; t < 8; ++t)
            y[t] = (unsigned)__shfl_xor((int)pk[t], 32, 64);

        union { unsigned u[4]; bf16x8 v; } pa0, pa1;
        if (half == 0) {
            pa0.u[0] = pk[0]; pa0.u[1] = pk[1]; pa0.u[2] = y[0];  pa0.u[3] = y[1];
            pa1.u[0] = pk[4]; pa1.u[1] = pk[5]; pa1.u[2] = y[4];  pa1.u[3] = y[5];
        } else {
            pa0.u[0] = y[2];  pa0.u[1] = y[3];  pa0.u[2] = pk[2]; pa0.u[3] = pk[3];
            pa1.u[0] = y[6];  pa1.u[1] = y[7];  pa1.u[2] = pk[6]; pa1.u[3] = pk[7];
        }

        #pragma unroll
        for (int ks = 0; ks < 2; ++ks) {
            const int R0 = kb + ks * 16 + half * 8;
            #pragma unroll
            for (int dh = 0; dh < 2; ++dh) {
                bf16x8 vf;
                const __bf16* vcol = V + dh * 32 + ql;
                #pragma unroll
                for (int j = 0; j < 8; ++j) {
                    int rr = R0 + j; if (rr > T_SEQ - 1) rr = T_SEQ - 1;
                    vf[j] = vcol[(size_t)rr * RS];
                }
                if (dh == 0)
                    oa0 = __builtin_amdgcn_mfma_f32_32x32x16_bf16(ks ? pa1.v : pa0.v, vf, oa0, 0, 0, 0);
                else
                    oa1 = __builtin_amdgcn_mfma_f32_32x32x16_bf16(ks ? pa1.v : pa0.v, vf, oa1, 0, 0, 0);
            }
        }
    }

    const float rinv = 1.f / l;
    __bf16* ob = o + ((size_t)b * T_SEQ) * DMODEL + hh * DHEAD;
    #pragma unroll
    for (int r = 0; r < 16; ++r) {
        const int q   = (r & 3) + 8 * (r >> 2) + 4 * half;
        const int row = qb + q;
        const float ri = __shfl(rinv, q, 64);
        if (row < T_SEQ) {
            ob[(size_t)row * DMODEL + ql]      = (__bf16)(oa0[r] * ri);
            ob[(size_t)row * DMODEL + 32 + ql] = (__bf16)(oa1[r] * ri);
        }
    }
}

// ---------------------------------------------------------------------------
// h = LayerNorm(h + t) * g + b; t (branch output) is bf16, h stays fp32;
// writes fp32 h and bf16 shadow.
// ---------------------------------------------------------------------------
__global__ __launch_bounds__(256)
void add_ln(float* __restrict__ hbuf, const __bf16* __restrict__ tbuf,
            const float* __restrict__ g, const float* __restrict__ b,
            __bf16* __restrict__ hb)
{
    const int row  = blockIdx.x * 4 + (threadIdx.x >> 6);
    const int lane = threadIdx.x & 63;
    float*        hp = hbuf + (size_t)row * DMODEL + lane * 8;
    const __bf16* tp = tbuf + (size_t)row * DMODEL + lane * 8;

    float xv[8];
    float4 h0 = *(const float4*)hp;   float4 h1 = *(const float4*)(hp + 4);
    bf16x8 tv = *(const bf16x8*)tp;
    xv[0] = h0.x + (float)tv[0]; xv[1] = h0.y + (float)tv[1];
    xv[2] = h0.z + (float)tv[2]; xv[3] = h0.w + (float)tv[3];
    xv[4] = h1.x + (float)tv[4]; xv[5] = h1.y + (float)tv[5];
    xv[6] = h1.z + (float)tv[6]; xv[7] = h1.w + (float)tv[7];

    float s = 0.f;
    #pragma unroll
    for (int j = 0; j < 8; ++j) s += xv[j];
    #pragma unroll
    for (int off = 32; off >= 1; off >>= 1) s += __shfl_xor(s, off, 64);
    float mean = s * (1.f / DMODEL);

    float vs = 0.f;
    #pragma unroll
    for (int j = 0; j < 8; ++j) { float d = xv[j] - mean; vs += d * d; }
    #pragma unroll
    for (int off = 32; off >= 1; off >>= 1) vs += __shfl_xor(vs, off, 64);
    float rstd = rsqrtf(vs * (1.f / DMODEL) + 1e-5f);

    float4 g0 = *(const float4*)(g + lane * 8);
    float4 g1 = *(const float4*)(g + lane * 8 + 4);
    float4 b0 = *(const float4*)(b + lane * 8);
    float4 b1 = *(const float4*)(b + lane * 8 + 4);
    float gg[8] = {g0.x, g0.y, g0.z, g0.w, g1.x, g1.y, g1.z, g1.w};
    float bb[8] = {b0.x, b0.y, b0.z, b0.w, b1.x, b1.y, b1.z, b1.w};

    float outv[8];
    bf16x8 ob;
    #pragma unroll
    for (int j = 0; j < 8; ++j) {
        outv[j] = (xv[j] - mean) * rstd * gg[j] + bb[j];
        ob[j] = (__bf16)outv[j];
    }
    *(float4*)hp       = *(float4*)&outv[0];
    *(float4*)(hp + 4) = *(float4*)&outv[4];
    *(bf16x8*)(hb + (size_t)row * DMODEL + lane * 8) = ob;
}

// ---------------------------------------------------------------------------
// Max-pool pass 1: grid (BATCH, TCHUNK).
// ---------------------------------------------------------------------------
__global__ __launch_bounds__(256)
void pool_p1(const float* __restrict__ hbuf, float* __restrict__ part)
{
    const int bb  = blockIdx.x;
    const int tc  = blockIdx.y;
    const int tid = threadIdx.x;
    const int t0  = tc * (T_SEQ / TCHUNK);
    const float* p = hbuf + ((size_t)bb * T_SEQ + t0) * DMODEL;

    float mx0 = -3.4e38f, mx1 = -3.4e38f;
    for (int t = 0; t < T_SEQ / TCHUNK; ++t) {
        mx0 = fmaxf(mx0, p[(size_t)t * DMODEL + tid]);
        mx1 = fmaxf(mx1, p[(size_t)t * DMODEL + 256 + tid]);
    }
    float* q = part + ((size_t)bb * TCHUNK + tc) * DMODEL;
    q[tid]       = mx0;
    q[tid + 256] = mx1;
}

// ---------------------------------------------------------------------------
// Max-pool pass 2 + classifier + log_softmax. One block per batch item.
// ---------------------------------------------------------------------------
__global__ __launch_bounds__(256)
void pool_p2(const float* __restrict__ part, const float* __restrict__ Wcls,
             const float* __restrict__ bcls, float* __restrict__ out)
{
    __shared__ float pooled[DMODEL];
    __shared__ float logits[8];
    const int bb  = blockIdx.x;
    const int tid = threadIdx.x;

    const float* q = part + (size_t)bb * TCHUNK * DMODEL;
    #pragma unroll
    for (int u = 0; u < 2; ++u) {
        const int d = tid + u * 256;
        float mx = -3.4e38f;
        for (int c = 0; c < TCHUNK; ++c) mx = fmaxf(mx, q[(size_t)c * DMODEL + d]);
        pooled[d] = mx;
    }
    __syncthreads();

    const int cls  = tid >> 5;
    const int lsub = tid & 31;
    const float* wr = Wcls + cls * DMODEL;
    float s = 0.f;
    #pragma unroll
    for (int u = 0; u < 16; ++u) {
        const int d = lsub + u * 32;
        s = fmaf(pooled[d], wr[d], s);
    }
    #pragma unroll
    for (int off = 16; off >= 1; off >>= 1) s += __shfl_xor(s, off, 32);
    if (lsub == 0) logits[cls] = s + bcls[cls];
    __syncthreads();

    if (tid == 0) {
        float mx = logits[0];
        for (int c = 1; c < 8; ++c) mx = fmaxf(mx, logits[c]);
        float se = 0.f;
        for (int c = 0; c < 8; ++c) se += expf(logits[c] - mx);
        float lse = logf(se) + mx;
        for (int c = 0; c < 8; ++c) out[bb * 8 + c] = logits[c] - lse;
    }
}

// ---------------------------------------------------------------------------
extern "C" void kernel_launch(void* const* d_in, const int* in_sizes, int n_in,
                              void* d_out, int out_size, void* d_ws, size_t ws_size,
                              hipStream_t stream)
{
    const float* x    = (const float*)d_in[0];
    const float* Wemb = (const float*)d_in[1];
    const float* bemb = (const float*)d_in[2];
    const float* Wqkv = (const float*)d_in[3];
    const float* bqkv = (const float*)d_in[4];
    const float* Wo   = (const float*)d_in[5];
    const float* bo   = (const float*)d_in[6];
    const float* W1   = (const float*)d_in[7];
    const float* b1f  = (const float*)d_in[8];
    const float* W2   = (const float*)d_in[9];
    const float* b2f  = (const float*)d_in[10];
    const float* g1   = (const float*)d_in[11];
    const float* be1  = (const float*)d_in[12];
    const float* g2   = (const float*)d_in[13];
    const float* be2  = (const float*)d_in[14];
    const float* Wcls = (const float*)d_in[15];
    const float* bcls = (const float*)d_in[16];
    float* out = (float*)d_out;

    // -------- workspace layout --------
    float*  h    = (float*)d_ws;                       // 8000x512 f32
    float*  tmpF = h + (size_t)MROWS * DMODEL;         // pool partials (8x25x512)
    __bf16* hb   = (__bf16*)(tmpF + (size_t)MROWS * DMODEL);   // 8000x512
    __bf16* qkvb = hb + (size_t)MROWS * DMODEL;        // 8000x1536
    __bf16* attb = qkvb + (size_t)MROWS * 3 * DMODEL;  // 8000x512
    __bf16* ff1b = qkvb;                               // alias: 8000x2048
    __bf16* xb   = attb + (size_t)MROWS * DMODEL;      // 8000x256
    __bf16* tmpB = xb + (size_t)MROWS * 256;           // 8000x512 bf16 branch out
    __bf16* wb   = tmpB + (size_t)MROWS * DMODEL;
    __bf16* wEmb = wb;
    __bf16* wQKV = wEmb + 512 * 256;
    __bf16* wWo  = wQKV + (size_t)NLAYER * 3 * DMODEL * DMODEL;
    __bf16* wW1  = wWo  + (size_t)NLAYER * DMODEL * DMODEL;
    __bf16* wW2  = wW1  + (size_t)NLAYER * FFDIM * DMODEL;

    dim3 blk(256);

    f2bf<<<dim3(MROWS * 256 / 1024), blk, 0, stream>>>(x, xb);
    f2bf<<<dim3(512 * 256 / 1024), blk, 0, stream>>>(Wemb, wEmb);
    f2bf<<<dim3(NLAYER * 3 * DMODEL * DMODEL / 1024), blk, 0, stream>>>(Wqkv, wQKV);
    f2bf<<<dim3(NLAYER * DMODEL * DMODEL / 1024), blk, 0, stream>>>(Wo, wWo);
    f2bf<<<dim3(NLAYER * FFDIM * DMODEL / 1024), blk, 0, stream>>>(W1, wW1);
    f2bf<<<dim3(NLAYER * DMODEL * FFDIM / 1024), blk, 0, stream>>>(W2, wW2);

    // embed + fused PE: writes h (fp32) and hb (bf16)
    gemm_bf16<true, true, false, true><<<dim3(4, 125), blk, 0, stream>>>(
        xb, wEmb, bemb, h, hb, MROWS, DMODEL, 256);

    for (int l = 0; l < NLAYER; ++l) {
        // QKV: N=1536
        gemm_bf16<false, true, false, false><<<dim3(12, 125), blk, 0, stream>>>(
            hb, wQKV + (size_t)l * 3 * DMODEL * DMODEL, bqkv + (size_t)l * 3 * DMODEL,
            nullptr, qkvb, MROWS, 3 * DMODEL, DMODEL);
        attn_mfma<<<dim3(512), blk, 0, stream>>>(qkvb, attb);
        // Wo: bf16 branch output
        gemm_bf16<false, true, false, false><<<dim3(4, 125), blk, 0, stream>>>(
            attb, wWo + (size_t)l * DMODEL * DMODEL, bo + (size_t)l * DMODEL,
            nullptr, tmpB, MROWS, DMODEL, DMODEL);
        add_ln<<<dim3(MROWS / 4), blk, 0, stream>>>(
            h, tmpB, g1 + (size_t)l * DMODEL, be1 + (size_t)l * DMODEL, hb);
        // FF1: N=2048 + ReLU
        gemm_bf16<false, true, true, false><<<dim3(16, 125), blk, 0, stream>>>(
            hb, wW1 + (size_t)l * FFDIM * DMODEL, b1f + (size_t)l * FFDIM,
            nullptr, ff1b, MROWS, FFDIM, DMODEL);
        // FF2: bf16 branch output
        gemm_bf16<false, true, false, false><<<dim3(4, 125), blk, 0, stream>>>(
            ff1b, wW2 + (size_t)l * DMODEL * FFDIM, b2f + (size_t)l * DMODEL,
            nullptr, tmpB, MROWS, DMODEL, FFDIM);
        add_ln<<<dim3(MROWS / 4), blk, 0, stream>>>(
            h, tmpB, g2 + (size_t)l * DMODEL, be2 + (size_t)l * DMODEL, hb);
    }

    pool_p1<<<dim3(BATCH, TCHUNK), blk, 0, stream>>>(h, tmpF);
    pool_p2<<<dim3(BATCH), blk, 0, stream>>>(tmpF, Wcls, bcls, out);
}